// Round 6
// baseline (679.120 us; speedup 1.0000x reference)
//
#include <hip/hip_runtime.h>

#define NN 50000
#define NE 800000

// ---------------- wave helpers ----------------
__device__ __forceinline__ float wsum64(float v) {
#pragma unroll
  for (int off = 32; off; off >>= 1) v += __shfl_xor(v, off, 64);
  return v;
}
__device__ __forceinline__ float lrelu(float x) { return x > 0.0f ? x : 0.2f * x; }
#define RFL(v) __builtin_amdgcn_readfirstlane(v)

// ---------------- CSR build ----------------
__global__ void zero_int_k(int* __restrict__ p, int n) {
  int i = blockIdx.x * 256 + threadIdx.x;
  if (i < n) p[i] = 0;
}

__global__ void count_deg_k(const int* __restrict__ dst, int* __restrict__ deg) {
  int e = blockIdx.x * 256 + threadIdx.x;
  if (e < NE) atomicAdd(&deg[dst[e]], 1);
}

__global__ __launch_bounds__(1024) void scan_k(const int* __restrict__ deg,
                                               int* __restrict__ row_ptr,
                                               int* __restrict__ cursor) {
  __shared__ int woff[16];
  int tid = threadIdx.x;
  int lane = tid & 63, wv = tid >> 6;
  const int CH = (NN + 1023) / 1024;  // 49
  int lo = tid * CH;
  int hi = lo + CH;
  if (lo > NN) lo = NN;
  if (hi > NN) hi = NN;
  int s = 0;
  for (int i = lo; i < hi; ++i) s += deg[i];
  int incl = s;
#pragma unroll
  for (int off = 1; off < 64; off <<= 1) {
    int t = __shfl_up(incl, off, 64);
    if (lane >= off) incl += t;
  }
  if (lane == 63) woff[wv] = incl;
  __syncthreads();
  if (tid == 0) {
    int run = 0;
#pragma unroll
    for (int w = 0; w < 16; ++w) { int t = woff[w]; woff[w] = run; run += t; }
    row_ptr[NN] = run;  // == NE
  }
  __syncthreads();
  int run = incl - s + woff[wv];
  for (int i = lo; i < hi; ++i) {
    row_ptr[i] = run;
    cursor[i] = run;
    run += deg[i];
  }
}

__global__ void fill_csr_k(const int* __restrict__ src, const int* __restrict__ dst,
                           int* __restrict__ cursor, int* __restrict__ csr_src) {
  int e = blockIdx.x * 256 + threadIdx.x;
  if (e < NE) {
    int pos = atomicAdd(&cursor[dst[e]], 1);
    csr_src[pos] = src[e];
  }
}

// ---------------- tiny precomputes ----------------
__global__ void compute_q_k(const float* __restrict__ W, const float* __restrict__ al,
                            const float* __restrict__ ar, float* __restrict__ Q, int KDIM) {
  int idx = blockIdx.x * 256 + threadIdx.x;
  if (idx >= KDIM * 8) return;
  int k = idx >> 3, c = idx & 7;
  int h = c & 3;
  const float* av = (c < 4 ? al : ar) + h * 64;
  const float* wrow = W + (size_t)k * 256 + h * 64;
  float s = 0.0f;
  for (int m = 0; m < 64; ++m) s += wrow[m] * av[m];
  Q[idx] = s;
}

__global__ void compute_m_k(const float* __restrict__ Wh2, const float* __restrict__ Wo,
                            float* __restrict__ M) {
  int row = blockIdx.x;  // 0..255
  int d = threadIdx.x;   // 0..63
  int h = row >> 6, k = row & 63;
  float s = 0.0f;
  for (int j = 0; j < 64; ++j)
    s += Wh2[k * 256 + h * 64 + j] * Wo[(h * 64 + j) * 64 + d];
  M[row * 64 + d] = s;
}

__global__ void compute_c_k(const float* __restrict__ bh2, const float* __restrict__ Wo,
                            const float* __restrict__ bo, float* __restrict__ cvec) {
  int d = threadIdx.x;
  if (d >= 64) return;
  float s = bo[d];
  for (int m = 0; m < 256; ++m) s += bh2[m] * Wo[m * 64 + d];
  cvec[d] = s;
}

// ---------------- el/er for layer 1 (from raw inputs) ----------------
__global__ __launch_bounds__(256) void eler_l1_k(const float* __restrict__ X,
                                                 const float* __restrict__ Q,
                                                 float* __restrict__ elp,
                                                 float* __restrict__ erp) {
  int n = RFL(blockIdx.x * 4 + (threadIdx.x >> 6));
  int lane = threadIdx.x & 63;
  float2 xv = *(const float2*)&X[(n << 7) + (lane << 1)];
  float4 qa0 = *(const float4*)&Q[(lane * 2) * 8];
  float4 qb0 = *(const float4*)&Q[(lane * 2) * 8 + 4];
  float4 qa1 = *(const float4*)&Q[(lane * 2 + 1) * 8];
  float4 qb1 = *(const float4*)&Q[(lane * 2 + 1) * 8 + 4];
  float p[8];
  p[0] = xv.x * qa0.x + xv.y * qa1.x; p[1] = xv.x * qa0.y + xv.y * qa1.y;
  p[2] = xv.x * qa0.z + xv.y * qa1.z; p[3] = xv.x * qa0.w + xv.y * qa1.w;
  p[4] = xv.x * qb0.x + xv.y * qb1.x; p[5] = xv.x * qb0.y + xv.y * qb1.y;
  p[6] = xv.x * qb0.z + xv.y * qb1.z; p[7] = xv.x * qb0.w + xv.y * qb1.w;
#pragma unroll
  for (int c = 0; c < 8; ++c) p[c] = wsum64(p[c]);
  if (lane == 0) {
    *(float4*)&elp[n << 2] = make_float4(p[0], p[1], p[2], p[3]);
    *(float4*)&erp[n << 2] = make_float4(p[4], p[5], p[6], p[7]);
  }
}

// ---------------- phase-1 helper: weights for one 64-edge chunk ----------------
// Computes wv (per-lane edge weights, 4 heads), stores (s, w4) to LDS, adds denoms.
__device__ __forceinline__ void weights_chunk(const float* __restrict__ el,
                                              const float4& er4,
                                              const int* __restrict__ csr_src,
                                              int j0, int cnt, int lane,
                                              int* __restrict__ s_l,
                                              float4* __restrict__ w_l,
                                              float& sw0, float& sw1,
                                              float& sw2, float& sw3) {
  float4 wv = make_float4(0.f, 0.f, 0.f, 0.f);
  int sv = 0;
  if (lane < cnt) {
    sv = csr_src[j0 + lane];
    float4 l4 = *(const float4*)&el[sv << 2];
    wv.x = __expf(lrelu(l4.x + er4.x));
    wv.y = __expf(lrelu(l4.y + er4.y));
    wv.z = __expf(lrelu(l4.z + er4.z));
    wv.w = __expf(lrelu(l4.w + er4.w));
  }
  s_l[lane] = sv;
  w_l[lane] = wv;
  sw0 += wsum64(wv.x);
  sw1 += wsum64(wv.y);
  sw2 += wsum64(wv.z);
  sw3 += wsum64(wv.w);
}

// ---------------- fused hidden layer (two-phase agg) ----------------
__global__ __launch_bounds__(256) void fused_hidden_k(
    const float* __restrict__ x, const float* __restrict__ el,
    const float* __restrict__ er, const float* __restrict__ W,
    const float* __restrict__ b, const float* __restrict__ Qn,
    const int* __restrict__ row_ptr, const int* __restrict__ csr_src,
    float* __restrict__ hout, float* __restrict__ eln, float* __restrict__ ern) {
  __shared__ float gs[4][1024];
  __shared__ int s_lds[4][64];
  __shared__ float4 w_lds[4][64];
  int wave = threadIdx.x >> 6, lane = threadIdx.x & 63;
  int base = (blockIdx.x * 4 + wave) * 4;
  float* gw = gs[wave];
  int* s_l = s_lds[wave];
  float4* w_l = w_lds[wave];
#pragma unroll 1
  for (int t = 0; t < 4; ++t) {
    int n = RFL(base + t);
    int beg = row_ptr[n], end = row_ptr[n + 1];
    float4 er4 = *(const float4*)&er[n << 2];
    float a0 = 0.f, a1 = 0.f, a2 = 0.f, a3 = 0.f;
    float sw0 = 0.f, sw1 = 0.f, sw2 = 0.f, sw3 = 0.f;
#pragma unroll 1
    for (int j0 = beg; j0 < end; j0 += 64) {
      int cnt = min(64, end - j0);
      weights_chunk(el, er4, csr_src, j0, cnt, lane, s_l, w_l, sw0, sw1, sw2, sw3);
      int j = 0;
      for (; j + 8 <= cnt; j += 8) {
        int t0 = RFL(s_l[j + 0]), t1 = RFL(s_l[j + 1]);
        int t2 = RFL(s_l[j + 2]), t3 = RFL(s_l[j + 3]);
        int t4 = RFL(s_l[j + 4]), t5 = RFL(s_l[j + 5]);
        int t6 = RFL(s_l[j + 6]), t7 = RFL(s_l[j + 7]);
        float x0 = x[(t0 << 6) + lane], x1 = x[(t1 << 6) + lane];
        float x2 = x[(t2 << 6) + lane], x3 = x[(t3 << 6) + lane];
        float x4 = x[(t4 << 6) + lane], x5 = x[(t5 << 6) + lane];
        float x6 = x[(t6 << 6) + lane], x7 = x[(t7 << 6) + lane];
#define FMA4(Q, X)                                 \
  do {                                             \
    float4 qq = (Q);                               \
    a0 = fmaf(qq.x, (X), a0);                      \
    a1 = fmaf(qq.y, (X), a1);                      \
    a2 = fmaf(qq.z, (X), a2);                      \
    a3 = fmaf(qq.w, (X), a3);                      \
  } while (0)
        FMA4(w_l[j + 0], x0); FMA4(w_l[j + 1], x1);
        FMA4(w_l[j + 2], x2); FMA4(w_l[j + 3], x3);
        FMA4(w_l[j + 4], x4); FMA4(w_l[j + 5], x5);
        FMA4(w_l[j + 6], x6); FMA4(w_l[j + 7], x7);
      }
      for (; j < cnt; ++j) {
        int t0 = RFL(s_l[j]);
        float x0 = x[(t0 << 6) + lane];
        FMA4(w_l[j], x0);
      }
#undef FMA4
    }
    float i0 = sw0 > 0.f ? 1.0f / sw0 : 0.f;
    float i1 = sw1 > 0.f ? 1.0f / sw1 : 0.f;
    float i2 = sw2 > 0.f ? 1.0f / sw2 : 0.f;
    float i3 = sw3 > 0.f ? 1.0f / sw3 : 0.f;
    gw[t * 256 + 0 * 64 + lane] = a0 * i0;
    gw[t * 256 + 1 * 64 + lane] = a1 * i1;
    gw[t * 256 + 2 * 64 + lane] = a2 * i2;
    gw[t * 256 + 3 * 64 + lane] = a3 * i3;
  }
  // GEMV: y[t][lane] = sum_row g[t][row] * W[k][h*64+lane], row=h*64+k
  float y0 = 0.f, y1 = 0.f, y2 = 0.f, y3 = 0.f;
  for (int rr = 0; rr < 256; rr += 4) {
#pragma unroll
    for (int u = 0; u < 4; ++u) {
      int row = rr + u;
      int h = row >> 6, k = row & 63;
      float sv = W[k * 256 + (h << 6) + lane];
      y0 = fmaf(gw[0 * 256 + row], sv, y0);
      y1 = fmaf(gw[1 * 256 + row], sv, y1);
      y2 = fmaf(gw[2 * 256 + row], sv, y2);
      y3 = fmaf(gw[3 * 256 + row], sv, y3);
    }
  }
  float bsum = b[lane] + b[64 + lane] + b[128 + lane] + b[192 + lane];
  float4 qa = *(const float4*)&Qn[lane * 8];
  float4 qb = *(const float4*)&Qn[lane * 8 + 4];
  float ys[4] = {y0, y1, y2, y3};
#pragma unroll
  for (int t = 0; t < 4; ++t) {
    int n = base + t;
    float yv = 0.25f * (ys[t] + bsum);
    hout[(n << 6) + lane] = yv;
    float e0 = wsum64(yv * qa.x), e1 = wsum64(yv * qa.y);
    float e2 = wsum64(yv * qa.z), e3 = wsum64(yv * qa.w);
    float r0 = wsum64(yv * qb.x), r1 = wsum64(yv * qb.y);
    float r2 = wsum64(yv * qb.z), r3 = wsum64(yv * qb.w);
    if (lane == 0) {
      *(float4*)&eln[n << 2] = make_float4(e0, e1, e2, e3);
      *(float4*)&ern[n << 2] = make_float4(r0, r1, r2, r3);
    }
  }
}

// ---------------- fused layer 1 (in_feat dim 128, two-phase agg) ----------------
__global__ __launch_bounds__(256) void fused_l1_k(
    const float* __restrict__ x, const float* __restrict__ el,
    const float* __restrict__ er, const float* __restrict__ W,
    const float* __restrict__ b, const float* __restrict__ Qn,
    const int* __restrict__ row_ptr, const int* __restrict__ csr_src,
    float* __restrict__ hout, float* __restrict__ eln, float* __restrict__ ern) {
  __shared__ float gs[4][2048];
  __shared__ int s_lds[4][64];
  __shared__ float4 w_lds[4][64];
  int wave = threadIdx.x >> 6, lane = threadIdx.x & 63;
  int base = (blockIdx.x * 4 + wave) * 4;
  float* gw = gs[wave];
  int* s_l = s_lds[wave];
  float4* w_l = w_lds[wave];
  int lane2 = lane << 1;
#pragma unroll 1
  for (int t = 0; t < 4; ++t) {
    int n = RFL(base + t);
    int beg = row_ptr[n], end = row_ptr[n + 1];
    float4 er4 = *(const float4*)&er[n << 2];
    float a0x = 0.f, a0y = 0.f, a1x = 0.f, a1y = 0.f;
    float a2x = 0.f, a2y = 0.f, a3x = 0.f, a3y = 0.f;
    float sw0 = 0.f, sw1 = 0.f, sw2 = 0.f, sw3 = 0.f;
#pragma unroll 1
    for (int j0 = beg; j0 < end; j0 += 64) {
      int cnt = min(64, end - j0);
      weights_chunk(el, er4, csr_src, j0, cnt, lane, s_l, w_l, sw0, sw1, sw2, sw3);
      int j = 0;
      for (; j + 8 <= cnt; j += 8) {
        int t0 = RFL(s_l[j + 0]), t1 = RFL(s_l[j + 1]);
        int t2 = RFL(s_l[j + 2]), t3 = RFL(s_l[j + 3]);
        int t4 = RFL(s_l[j + 4]), t5 = RFL(s_l[j + 5]);
        int t6 = RFL(s_l[j + 6]), t7 = RFL(s_l[j + 7]);
        float2 x0 = *(const float2*)&x[(t0 << 7) + lane2];
        float2 x1 = *(const float2*)&x[(t1 << 7) + lane2];
        float2 x2 = *(const float2*)&x[(t2 << 7) + lane2];
        float2 x3 = *(const float2*)&x[(t3 << 7) + lane2];
        float2 x4 = *(const float2*)&x[(t4 << 7) + lane2];
        float2 x5 = *(const float2*)&x[(t5 << 7) + lane2];
        float2 x6 = *(const float2*)&x[(t6 << 7) + lane2];
        float2 x7 = *(const float2*)&x[(t7 << 7) + lane2];
#define FMA8(Q, X)                                   \
  do {                                               \
    float4 qq = (Q);                                 \
    a0x = fmaf(qq.x, (X).x, a0x);                    \
    a0y = fmaf(qq.x, (X).y, a0y);                    \
    a1x = fmaf(qq.y, (X).x, a1x);                    \
    a1y = fmaf(qq.y, (X).y, a1y);                    \
    a2x = fmaf(qq.z, (X).x, a2x);                    \
    a2y = fmaf(qq.z, (X).y, a2y);                    \
    a3x = fmaf(qq.w, (X).x, a3x);                    \
    a3y = fmaf(qq.w, (X).y, a3y);                    \
  } while (0)
        FMA8(w_l[j + 0], x0); FMA8(w_l[j + 1], x1);
        FMA8(w_l[j + 2], x2); FMA8(w_l[j + 3], x3);
        FMA8(w_l[j + 4], x4); FMA8(w_l[j + 5], x5);
        FMA8(w_l[j + 6], x6); FMA8(w_l[j + 7], x7);
      }
      for (; j < cnt; ++j) {
        int t0 = RFL(s_l[j]);
        float2 x0 = *(const float2*)&x[(t0 << 7) + lane2];
        FMA8(w_l[j], x0);
      }
#undef FMA8
    }
    float i0 = sw0 > 0.f ? 1.0f / sw0 : 0.f;
    float i1 = sw1 > 0.f ? 1.0f / sw1 : 0.f;
    float i2 = sw2 > 0.f ? 1.0f / sw2 : 0.f;
    float i3 = sw3 > 0.f ? 1.0f / sw3 : 0.f;
    *(float2*)&gw[t * 512 + 0 * 128 + lane2] = make_float2(a0x * i0, a0y * i0);
    *(float2*)&gw[t * 512 + 1 * 128 + lane2] = make_float2(a1x * i1, a1y * i1);
    *(float2*)&gw[t * 512 + 2 * 128 + lane2] = make_float2(a2x * i2, a2y * i2);
    *(float2*)&gw[t * 512 + 3 * 128 + lane2] = make_float2(a3x * i3, a3y * i3);
  }
  // GEMV: row = h*128+k, sv = W[k*256 + h*64 + lane]
  float y0 = 0.f, y1 = 0.f, y2 = 0.f, y3 = 0.f;
  for (int rr = 0; rr < 512; rr += 4) {
#pragma unroll
    for (int u = 0; u < 4; ++u) {
      int row = rr + u;
      int h = row >> 7, k = row & 127;
      float sv = W[k * 256 + (h << 6) + lane];
      y0 = fmaf(gw[0 * 512 + row], sv, y0);
      y1 = fmaf(gw[1 * 512 + row], sv, y1);
      y2 = fmaf(gw[2 * 512 + row], sv, y2);
      y3 = fmaf(gw[3 * 512 + row], sv, y3);
    }
  }
  float bsum = b[lane] + b[64 + lane] + b[128 + lane] + b[192 + lane];
  float4 qa = *(const float4*)&Qn[lane * 8];
  float4 qb = *(const float4*)&Qn[lane * 8 + 4];
  float ys[4] = {y0, y1, y2, y3};
#pragma unroll
  for (int t = 0; t < 4; ++t) {
    int n = base + t;
    float yv = 0.25f * (ys[t] + bsum);
    hout[(n << 6) + lane] = yv;
    float e0 = wsum64(yv * qa.x), e1 = wsum64(yv * qa.y);
    float e2 = wsum64(yv * qa.z), e3 = wsum64(yv * qa.w);
    float r0 = wsum64(yv * qb.x), r1 = wsum64(yv * qb.y);
    float r2 = wsum64(yv * qb.z), r3 = wsum64(yv * qb.w);
    if (lane == 0) {
      *(float4*)&eln[n << 2] = make_float4(e0, e1, e2, e3);
      *(float4*)&ern[n << 2] = make_float4(r0, r1, r2, r3);
    }
  }
}

// ---------------- fused final (two-phase agg + GEMV(M) + LayerNorm) -------------
__global__ __launch_bounds__(256) void fused_final_k(
    const float* __restrict__ x, const float* __restrict__ el,
    const float* __restrict__ er, const float* __restrict__ M,
    const float* __restrict__ cvec, const int* __restrict__ row_ptr,
    const int* __restrict__ csr_src, float* __restrict__ out) {
  __shared__ float gs[4][1024];
  __shared__ int s_lds[4][64];
  __shared__ float4 w_lds[4][64];
  int wave = threadIdx.x >> 6, lane = threadIdx.x & 63;
  int base = (blockIdx.x * 4 + wave) * 4;
  float* gw = gs[wave];
  int* s_l = s_lds[wave];
  float4* w_l = w_lds[wave];
#pragma unroll 1
  for (int t = 0; t < 4; ++t) {
    int n = RFL(base + t);
    int beg = row_ptr[n], end = row_ptr[n + 1];
    float4 er4 = *(const float4*)&er[n << 2];
    float a0 = 0.f, a1 = 0.f, a2 = 0.f, a3 = 0.f;
    float sw0 = 0.f, sw1 = 0.f, sw2 = 0.f, sw3 = 0.f;
#pragma unroll 1
    for (int j0 = beg; j0 < end; j0 += 64) {
      int cnt = min(64, end - j0);
      weights_chunk(el, er4, csr_src, j0, cnt, lane, s_l, w_l, sw0, sw1, sw2, sw3);
      int j = 0;
      for (; j + 8 <= cnt; j += 8) {
        int t0 = RFL(s_l[j + 0]), t1 = RFL(s_l[j + 1]);
        int t2 = RFL(s_l[j + 2]), t3 = RFL(s_l[j + 3]);
        int t4 = RFL(s_l[j + 4]), t5 = RFL(s_l[j + 5]);
        int t6 = RFL(s_l[j + 6]), t7 = RFL(s_l[j + 7]);
        float x0 = x[(t0 << 6) + lane], x1 = x[(t1 << 6) + lane];
        float x2 = x[(t2 << 6) + lane], x3 = x[(t3 << 6) + lane];
        float x4 = x[(t4 << 6) + lane], x5 = x[(t5 << 6) + lane];
        float x6 = x[(t6 << 6) + lane], x7 = x[(t7 << 6) + lane];
#define FMA4(Q, X)                                 \
  do {                                             \
    float4 qq = (Q);                               \
    a0 = fmaf(qq.x, (X), a0);                      \
    a1 = fmaf(qq.y, (X), a1);                      \
    a2 = fmaf(qq.z, (X), a2);                      \
    a3 = fmaf(qq.w, (X), a3);                      \
  } while (0)
        FMA4(w_l[j + 0], x0); FMA4(w_l[j + 1], x1);
        FMA4(w_l[j + 2], x2); FMA4(w_l[j + 3], x3);
        FMA4(w_l[j + 4], x4); FMA4(w_l[j + 5], x5);
        FMA4(w_l[j + 6], x6); FMA4(w_l[j + 7], x7);
      }
      for (; j < cnt; ++j) {
        int t0 = RFL(s_l[j]);
        float x0 = x[(t0 << 6) + lane];
        FMA4(w_l[j], x0);
      }
#undef FMA4
    }
    float i0 = sw0 > 0.f ? 1.0f / sw0 : 0.f;
    float i1 = sw1 > 0.f ? 1.0f / sw1 : 0.f;
    float i2 = sw2 > 0.f ? 1.0f / sw2 : 0.f;
    float i3 = sw3 > 0.f ? 1.0f / sw3 : 0.f;
    gw[t * 256 + 0 * 64 + lane] = a0 * i0;
    gw[t * 256 + 1 * 64 + lane] = a1 * i1;
    gw[t * 256 + 2 * 64 + lane] = a2 * i2;
    gw[t * 256 + 3 * 64 + lane] = a3 * i3;
  }
  float y0 = 0.f, y1 = 0.f, y2 = 0.f, y3 = 0.f;
  for (int rr = 0; rr < 256; rr += 4) {
#pragma unroll
    for (int u = 0; u < 4; ++u) {
      int row = rr + u;
      float sv = M[(row << 6) + lane];
      y0 = fmaf(gw[0 * 256 + row], sv, y0);
      y1 = fmaf(gw[1 * 256 + row], sv, y1);
      y2 = fmaf(gw[2 * 256 + row], sv, y2);
      y3 = fmaf(gw[3 * 256 + row], sv, y3);
    }
  }
  float cl = cvec[lane];
  float ys[4] = {y0 + cl, y1 + cl, y2 + cl, y3 + cl};
#pragma unroll
  for (int t = 0; t < 4; ++t) {
    int n = base + t;
    float y = ys[t];
    float mu = wsum64(y) * (1.0f / 64.0f);
    float dv = y - mu;
    float var = wsum64(dv * dv) * (1.0f / 64.0f);
    out[(n << 6) + lane] = dv * rsqrtf(var + 1e-5f);
  }
}

// ---------------- launch ----------------
extern "C" void kernel_launch(void* const* d_in, const int* in_sizes, int n_in,
                              void* d_out, int out_size, void* d_ws, size_t ws_size,
                              hipStream_t stream) {
  const float* in_feat = (const float*)d_in[0];
  const int* src = (const int*)d_in[1];
  const int* dst = (const int*)d_in[2];
  const float* W1 = (const float*)d_in[3];
  const float* al1 = (const float*)d_in[4];
  const float* ar1 = (const float*)d_in[5];
  const float* b1 = (const float*)d_in[6];
  const float* Wh = (const float*)d_in[7];   // [3][64][256]
  const float* alh = (const float*)d_in[8];  // [3][4][64]
  const float* arh = (const float*)d_in[9];  // [3][4][64]
  const float* bh = (const float*)d_in[10];  // [3][256]
  const float* Wo = (const float*)d_in[11];  // [256][64]
  const float* bo = (const float*)d_in[12];  // [64]
  float* out = (float*)d_out;

  char* ws = (char*)d_ws;
  size_t off = 0;
  auto alloc = [&](size_t bytes) {
    void* p = ws + off;
    off = (off + bytes + 255) & ~(size_t)255;
    return p;
  };
  float* h_a = (float*)alloc((size_t)NN * 64 * 4);
  float* h_b = (float*)alloc((size_t)NN * 64 * 4);
  float* el_a = (float*)alloc((size_t)NN * 4 * 4);
  float* er_a = (float*)alloc((size_t)NN * 4 * 4);
  float* el_b = (float*)alloc((size_t)NN * 4 * 4);
  float* er_b = (float*)alloc((size_t)NN * 4 * 4);
  float* Q1 = (float*)alloc(128 * 8 * 4);
  float* Q2 = (float*)alloc(64 * 8 * 4);
  float* Q3 = (float*)alloc(64 * 8 * 4);
  float* Q4 = (float*)alloc(64 * 8 * 4);
  float* M = (float*)alloc(256 * 64 * 4);
  float* cvec = (float*)alloc(64 * 4);
  int* deg = (int*)alloc((size_t)NN * 4);
  int* row_ptr = (int*)alloc((size_t)(NN + 1) * 4);
  int* cursor = (int*)alloc((size_t)NN * 4);
  int* csr_src = (int*)alloc((size_t)NE * 4);
  (void)ws_size; (void)in_sizes; (void)n_in; (void)out_size;

  // CSR build
  zero_int_k<<<(NN + 255) / 256, 256, 0, stream>>>(deg, NN);
  count_deg_k<<<(NE + 255) / 256, 256, 0, stream>>>(dst, deg);
  scan_k<<<1, 1024, 0, stream>>>(deg, row_ptr, cursor);
  fill_csr_k<<<(NE + 255) / 256, 256, 0, stream>>>(src, dst, cursor, csr_src);

  // tiny precomputes
  compute_q_k<<<4, 256, 0, stream>>>(W1, al1, ar1, Q1, 128);
  compute_q_k<<<2, 256, 0, stream>>>(Wh + 0 * 64 * 256, alh + 0 * 256, arh + 0 * 256, Q2, 64);
  compute_q_k<<<2, 256, 0, stream>>>(Wh + 1 * 64 * 256, alh + 1 * 256, arh + 1 * 256, Q3, 64);
  compute_q_k<<<2, 256, 0, stream>>>(Wh + 2 * 64 * 256, alh + 2 * 256, arh + 2 * 256, Q4, 64);
  compute_m_k<<<256, 64, 0, stream>>>(Wh + 2 * 64 * 256, Wo, M);
  compute_c_k<<<1, 64, 0, stream>>>(bh + 2 * 256, Wo, bo, cvec);

  const int FUSED_GRID = NN / 16;  // 3125
  const int ELER_GRID = NN / 4;    // 12500

  // layer 1
  eler_l1_k<<<ELER_GRID, 256, 0, stream>>>(in_feat, Q1, el_a, er_a);
  fused_l1_k<<<FUSED_GRID, 256, 0, stream>>>(in_feat, el_a, er_a, W1, b1, Q2,
                                             row_ptr, csr_src, h_a, el_b, er_b);
  // hidden layers
  fused_hidden_k<<<FUSED_GRID, 256, 0, stream>>>(h_a, el_b, er_b, Wh + 0 * 64 * 256,
                                                 bh + 0 * 256, Q3, row_ptr, csr_src,
                                                 h_b, el_a, er_a);
  fused_hidden_k<<<FUSED_GRID, 256, 0, stream>>>(h_b, el_a, er_a, Wh + 1 * 64 * 256,
                                                 bh + 1 * 256, Q4, row_ptr, csr_src,
                                                 h_a, el_b, er_b);
  // final layer + out_ln + LayerNorm
  fused_final_k<<<FUSED_GRID, 256, 0, stream>>>(h_a, el_b, er_b, M, cvec,
                                                row_ptr, csr_src, out);
}